// Round 3
// baseline (152.977 us; speedup 1.0000x reference)
//
#include <hip/hip_runtime.h>

// VectorQuantizer: B=16,T=8192,D=64,K=1024
// out = [quantized 131072x64 f32][indices 131072 as f32]
// Round 11: delete LDS + barriers. r9/r10 showed waves stalled ~75% with
// per-chunk __syncthreads convoying 4 blocks/CU (Occupancy 25%, MfmaUtil 26%,
// HBM 8%). wpk is only 256KB and L2/L1-resident: read fragments straight
// from global with a named-register ping-pong prefetch (1 cbl ahead).
// Every wave free-runs; no s_barrier anywhere in the main kernel.
#define MTOK  131072
#define DIMD  64
#define KCODE 1024
#define TPB   128        // tokens per block = 4 waves x 32 tokens

typedef __bf16 bf16x8 __attribute__((ext_vector_type(8)));
typedef float  f32x4  __attribute__((ext_vector_type(4)));

__device__ __forceinline__ f32x4 mfma16(bf16x8 a, bf16x8 b, f32x4 c) {
    return __builtin_amdgcn_mfma_f32_16x16x32_bf16(a, b, c, 0, 0, 0);
}

// ---- prep: pack W into MFMA-fragment order + e2 tables (r5-verified) ----
// wpk element offset = cb*2048 + win*512 + lane*8
// win: 0=hi d0-31, 1=hi d32-63, 2=lo d0-31, 3=lo d32-63
// lane=(q,m): frag = w[cb*16+m][(win&1)*32+q*8 ..+8]
__global__ __launch_bounds__(256) void prep_kernel(
    const float* __restrict__ w, __bf16* __restrict__ wpk,
    float* __restrict__ e2n, float* __restrict__ e2) {
    int b   = blockIdx.x;
    int tid = threadIdx.x;
    if (b < 64) {                       // pack blocks
        int cb  = b;
        int win = tid >> 6, lane = tid & 63;
        int q = lane >> 4, m = lane & 15;
        int k = cb * 16 + m;
        int d0 = (win & 1) * 32 + q * 8;
        const float* src = w + (size_t)k * DIMD + d0;
        float4 v0 = *(const float4*)(src);
        float4 v1 = *(const float4*)(src + 4);
        float f[8] = {v0.x, v0.y, v0.z, v0.w, v1.x, v1.y, v1.z, v1.w};
        bf16x8 o;
#pragma unroll
        for (int j = 0; j < 8; ++j) {
            __bf16 h = (__bf16)f[j];
            o[j] = (win < 2) ? h : (__bf16)(f[j] - (float)h);
        }
        *(bf16x8*)(wpk + ((size_t)(cb * 4 + win) * 64 + lane) * 8) = o;
    } else {                            // e2: one code/thread, exact r1 fma order
        int k2 = (b - 64) * 256 + tid;
        const float4* row = (const float4*)(w + (size_t)k2 * DIMD);
        float s = 0.f;
#pragma unroll
        for (int i = 0; i < 16; ++i) {
            float4 v = row[i];
            s = fmaf(v.x, v.x, s); s = fmaf(v.y, v.y, s);
            s = fmaf(v.z, v.z, s); s = fmaf(v.w, v.w, s);
        }
        e2[k2]  = s;
        e2n[k2] = -0.5f * s;
    }
}

__global__ __launch_bounds__(256, 4) void vq_main(
    const float* __restrict__ x, const float* __restrict__ wfull,
    const __bf16* __restrict__ wpk, const float* __restrict__ e2n_g,
    const float* __restrict__ e2_g, float* __restrict__ out) {

    const int tid  = threadIdx.x;
    const int blk  = blockIdx.x;
    const int lane = tid & 63;
    const int wv   = tid >> 6;      // wave -> tokens wv*32..+32
    const int q    = lane >> 4;
    const int m    = lane & 15;
    const size_t tok0 = (size_t)blk * TPB + wv * 32;   // wave's first token

    // ---- x fragments straight from global, hi/lo split in registers ----
    bf16x8 bx[2][4];
#pragma unroll
    for (int tg = 0; tg < 2; ++tg) {
        const float* xr = x + (tok0 + tg * 16 + m) * DIMD;
#pragma unroll
        for (int h = 0; h < 2; ++h) {
            float4 v0 = *(const float4*)(xr + h * 32 + q * 8);
            float4 v1 = *(const float4*)(xr + h * 32 + q * 8 + 4);
            float f[8] = {v0.x, v0.y, v0.z, v0.w, v1.x, v1.y, v1.z, v1.w};
            bf16x8 hi, lo;
#pragma unroll
            for (int j = 0; j < 8; ++j) {
                __bf16 hh = (__bf16)f[j];
                hi[j] = hh;
                lo[j] = (__bf16)(f[j] - (float)hh);
            }
            bx[tg][h]     = hi;
            bx[tg][2 + h] = lo;
        }
    }

    float b1[2], b2[2]; int i1[2];
#pragma unroll
    for (int tg = 0; tg < 2; ++tg) { b1[tg] = -3e38f; b2[tg] = -3e38f; i1[tg] = 0; }

    // per-lane fragment base pointers (advance by cb*2048 elems / cb*16 floats)
    const __bf16* wp = wpk + (size_t)lane * 8;
    const float*  ep = e2n_g + q * 4;

    // r9-verified numerics: 6-deep chain per token group, interleaved pair.
    auto compute = [&](const bf16x8& A0, const bf16x8& A1, const bf16x8& A2,
                       const bf16x8& A3, const f32x4& EE, int cbase) {
        __builtin_amdgcn_s_setprio(1);
        f32x4 t0 = mfma16(A0, bx[0][0], EE);   // w_hi*x_hi d0-31
        f32x4 t1 = mfma16(A0, bx[1][0], EE);
        t0 = mfma16(A1, bx[0][1], t0);         // w_hi*x_hi d32-63
        t1 = mfma16(A1, bx[1][1], t1);
        t0 = mfma16(A0, bx[0][2], t0);         // w_hi*x_lo
        t1 = mfma16(A0, bx[1][2], t1);
        t0 = mfma16(A1, bx[0][3], t0);
        t1 = mfma16(A1, bx[1][3], t1);
        t0 = mfma16(A2, bx[0][0], t0);         // w_lo*x_hi
        t1 = mfma16(A2, bx[1][0], t1);
        t0 = mfma16(A3, bx[0][1], t0);
        t1 = mfma16(A3, bx[1][1], t1);
        __builtin_amdgcn_s_setprio(0);
        // Tracker: top-1 (value+idx, strict > => ties keep lower code)
        // + top-2 value (med3). Same op order as verified r5 numerics.
#pragma unroll
        for (int r = 0; r < 4; ++r) {
            float a  = t0[r];
            int iv   = cbase + q * 4 + r;
            bool gt  = a > b1[0];
            i1[0] = gt ? iv : i1[0];
            b2[0] = __builtin_amdgcn_fmed3f(a, b1[0], b2[0]);
            b1[0] = fmaxf(a, b1[0]);
        }
#pragma unroll
        for (int r = 0; r < 4; ++r) {
            float a  = t1[r];
            int iv   = cbase + q * 4 + r;
            bool gt  = a > b1[1];
            i1[1] = gt ? iv : i1[1];
            b2[1] = __builtin_amdgcn_fmed3f(a, b1[1], b2[1]);
            b1[1] = fmaxf(a, b1[1]);
        }
    };

    // ---- main loop: 64 code blocks of 16; named-set ping-pong prefetch ----
    bf16x8 Pa0, Pa1, Pa2, Pa3, Pb0, Pb1, Pb2, Pb3;
    f32x4  Ea, Eb;

    {   // preload cb=0 -> set A
        const __bf16* wc = wp;
        Pa0 = *(const bf16x8*)(wc + 0);
        Pa1 = *(const bf16x8*)(wc + 512);
        Pa2 = *(const bf16x8*)(wc + 1024);
        Pa3 = *(const bf16x8*)(wc + 1536);
        Ea  = *(const f32x4*)(ep);
    }

    for (int cb = 0; cb < 64; cb += 2) {
        {   // prefetch cb+1 -> set B (issues before set-A compute waits)
            const __bf16* wc = wp + (size_t)(cb + 1) * 2048;
            Pb0 = *(const bf16x8*)(wc + 0);
            Pb1 = *(const bf16x8*)(wc + 512);
            Pb2 = *(const bf16x8*)(wc + 1024);
            Pb3 = *(const bf16x8*)(wc + 1536);
            Eb  = *(const f32x4*)(ep + (cb + 1) * 16);
        }
        compute(Pa0, Pa1, Pa2, Pa3, Ea, cb * 16);
        if (cb + 2 < 64) {   // prefetch cb+2 -> set A
            const __bf16* wc = wp + (size_t)(cb + 2) * 2048;
            Pa0 = *(const bf16x8*)(wc + 0);
            Pa1 = *(const bf16x8*)(wc + 512);
            Pa2 = *(const bf16x8*)(wc + 1024);
            Pa3 = *(const bf16x8*)(wc + 1536);
            Ea  = *(const f32x4*)(ep + (cb + 2) * 16);
        }
        compute(Pb0, Pb1, Pb2, Pb3, Eb, (cb + 1) * 16);
    }

    // ---- cross-quad merge: lanes m,m+16,m+32,m+48 hold disjoint code sets ----
    float B1f[2], B2f[2]; int I1f[2];
#pragma unroll
    for (int tg = 0; tg < 2; ++tg) {
        float B1 = b1[tg], B2 = b2[tg]; int I1 = i1[tg];
#pragma unroll
        for (int mask = 16; mask <= 32; mask <<= 1) {
            float ob1 = __shfl_xor(B1, mask);
            float ob2 = __shfl_xor(B2, mask);
            int   oi  = __shfl_xor(I1, mask);
            bool take = (ob1 > B1) || (ob1 == B1 && oi < I1);
            B2 = fmaxf(fminf(ob1, B1), fmaxf(ob2, B2));
            I1 = take ? oi : I1;
            B1 = fmaxf(ob1, B1);
        }
        B1f[tg] = B1; B2f[tg] = B2; I1f[tg] = I1;   // replicated across quads
    }

    // token t (0..31) of this wave -> its index; lanes 0..31 own token lane
    int myidx;
    {
        int src = lane & 15;
        int v0 = __shfl(I1f[0], src);
        int v1 = __shfl(I1f[1], src);
        myidx = ((lane >> 4) & 1) ? v1 : v0;
    }

    // ---- ballot-driven exact fp32 rescan of near-ties (round-1 numerics) ----
#pragma unroll
    for (int tg = 0; tg < 2; ++tg) {
        unsigned long long msk =
            __ballot((lane < 16) && (B1f[tg] - B2f[tg] < 2e-3f));
        while (msk) {
            int mm = __ffsll((unsigned long long)msk) - 1;
            msk &= msk - 1;
            int tloc = tg * 16 + mm;              // token within this wave (0..31)
            const float4* xr = (const float4*)(x + (tok0 + tloc) * DIMD);
            float bv = 3e38f; int bi = 0;
            for (int j = 0; j < 16; ++j) {
                int k = lane * 16 + j;
                const float4* wr = (const float4*)(wfull + (size_t)k * DIMD);
                float s = 0.f;
#pragma unroll
                for (int i = 0; i < 16; ++i) {
                    float4 xv = xr[i], wv4 = wr[i];
                    s = fmaf(xv.x, wv4.x, s); s = fmaf(xv.y, wv4.y, s);
                    s = fmaf(xv.z, wv4.z, s); s = fmaf(xv.w, wv4.w, s);
                }
                float dv = fmaf(-2.f, s, e2_g[k]);
                if (dv < bv) { bv = dv; bi = k; }  // ties -> lower k
            }
#pragma unroll
            for (int mask2 = 1; mask2 <= 32; mask2 <<= 1) {
                float ov = __shfl_xor(bv, mask2);
                int   oi = __shfl_xor(bi, mask2);
                bool take = (ov < bv) || (ov == bv && oi < bi);
                bv = take ? ov : bv;
                bi = take ? oi : bi;
            }
            myidx = (lane == tloc) ? bi : myidx;
        }
    }

    // ---- outputs (nontemporal: pure streaming, keep L2 for wpk/e2n) ----
    if (lane < 32)
        __builtin_nontemporal_store((float)myidx,
                                    out + (size_t)MTOK * DIMD + tok0 + lane);

    // coalesced gather: per j, wave writes one contiguous 1KB segment;
    // codebook row read cooperatively (16 lanes per row, contiguous 256B)
    {
        float* obase = out + tok0 * DIMD;
#pragma unroll
        for (int j = 0; j < 8; ++j) {
            int srcl = j * 4 + (lane >> 4);        // token 0..31
            int gi   = __shfl(myidx, srcl);
            f32x4 v = *(const f32x4*)(wfull + (size_t)gi * DIMD + (lane & 15) * 4);
            __builtin_nontemporal_store(v, (f32x4*)(obase + j * 256 + lane * 4));
        }
    }
}

extern "C" void kernel_launch(void* const* d_in, const int* in_sizes, int n_in,
                              void* d_out, int out_size, void* d_ws, size_t ws_size,
                              hipStream_t stream) {
    const float* x = (const float*)d_in[0];
    const float* w = (const float*)d_in[1];
    float* out = (float*)d_out;

    // ws: [wpk 256K][e2n 4K][e2 4K]
    __bf16* wpk = (__bf16*)d_ws;
    float*  e2n = (float*)((char*)d_ws + 262144);
    float*  e2  = (float*)((char*)d_ws + 266240);

    prep_kernel<<<68, 256, 0, stream>>>(w, wpk, e2n, e2);
    vq_main<<<MTOK / TPB, 256, 0, stream>>>(x, w, wpk, e2n, e2, out);
}

// Round 5
// 142.868 us; speedup vs baseline: 1.0708x; 1.0708x over previous
//
#include <hip/hip_runtime.h>

// VectorQuantizer: B=16,T=8192,D=64,K=1024
// out = [quantized 131072x64 f32][indices 131072 as f32]
// Round 13 = Round 12 resubmitted verbatim (r12 bench died to container
// acquisition failure, not kernel). Theory under test: MfmaUtil pinned at
// ~25% across r8-r11 because each wave ran only 2 independent 6-deep
// dependent-MFMA chains (~240cy critical path vs ~58cy issue); with
// 4 waves/SIMD that caps pipe busy at 4*58/240 ~ 24%. This version:
// 64 tokens/wave = 4 INDEPENDENT 6-deep chains per code-block (24 MFMA
// per 5 loads), half the waves (2 blocks/CU), half the L2 wpk traffic,
// no barriers, no LDS, no cross-chain combine adds.
#define MTOK  131072
#define DIMD  64
#define KCODE 1024
#define TPB   256        // tokens per block = 4 waves x 64 tokens

typedef __bf16 bf16x8 __attribute__((ext_vector_type(8)));
typedef float  f32x4  __attribute__((ext_vector_type(4)));

__device__ __forceinline__ f32x4 mfma16(bf16x8 a, bf16x8 b, f32x4 c) {
    return __builtin_amdgcn_mfma_f32_16x16x32_bf16(a, b, c, 0, 0, 0);
}

// ---- prep: pack W into MFMA-fragment order + e2 tables (r5-verified) ----
// wpk element offset = cb*2048 + win*512 + lane*8
// win: 0=hi d0-31, 1=hi d32-63, 2=lo d0-31, 3=lo d32-63
// lane=(q,m): frag = w[cb*16+m][(win&1)*32+q*8 ..+8]
__global__ __launch_bounds__(256) void prep_kernel(
    const float* __restrict__ w, __bf16* __restrict__ wpk,
    float* __restrict__ e2n, float* __restrict__ e2) {
    int b   = blockIdx.x;
    int tid = threadIdx.x;
    if (b < 64) {                       // pack blocks
        int cb  = b;
        int win = tid >> 6, lane = tid & 63;
        int q = lane >> 4, m = lane & 15;
        int k = cb * 16 + m;
        int d0 = (win & 1) * 32 + q * 8;
        const float* src = w + (size_t)k * DIMD + d0;
        float4 v0 = *(const float4*)(src);
        float4 v1 = *(const float4*)(src + 4);
        float f[8] = {v0.x, v0.y, v0.z, v0.w, v1.x, v1.y, v1.z, v1.w};
        bf16x8 o;
#pragma unroll
        for (int j = 0; j < 8; ++j) {
            __bf16 h = (__bf16)f[j];
            o[j] = (win < 2) ? h : (__bf16)(f[j] - (float)h);
        }
        *(bf16x8*)(wpk + ((size_t)(cb * 4 + win) * 64 + lane) * 8) = o;
    } else {                            // e2: one code/thread, exact r1 fma order
        int k2 = (b - 64) * 256 + tid;
        const float4* row = (const float4*)(w + (size_t)k2 * DIMD);
        float s = 0.f;
#pragma unroll
        for (int i = 0; i < 16; ++i) {
            float4 v = row[i];
            s = fmaf(v.x, v.x, s); s = fmaf(v.y, v.y, s);
            s = fmaf(v.z, v.z, s); s = fmaf(v.w, v.w, s);
        }
        e2[k2]  = s;
        e2n[k2] = -0.5f * s;
    }
}

__global__ __launch_bounds__(256, 2) void vq_main(
    const float* __restrict__ x, const float* __restrict__ wfull,
    const __bf16* __restrict__ wpk, const float* __restrict__ e2n_g,
    const float* __restrict__ e2_g, float* __restrict__ out) {

    const int tid  = threadIdx.x;
    const int blk  = blockIdx.x;
    const int lane = tid & 63;
    const int wv   = tid >> 6;      // wave -> tokens wv*64..+64
    const int q    = lane >> 4;
    const int m    = lane & 15;
    const size_t tok0 = (size_t)blk * TPB + wv * 64;   // wave's first token

    // ---- x fragments straight from global, hi/lo split in registers ----
    // 4 token groups of 16: token t = tg*16 + m
    bf16x8 bx[4][4];
#pragma unroll
    for (int tg = 0; tg < 4; ++tg) {
        const float* xr = x + (tok0 + tg * 16 + m) * DIMD;
#pragma unroll
        for (int h = 0; h < 2; ++h) {
            float4 v0 = *(const float4*)(xr + h * 32 + q * 8);
            float4 v1 = *(const float4*)(xr + h * 32 + q * 8 + 4);
            float f[8] = {v0.x, v0.y, v0.z, v0.w, v1.x, v1.y, v1.z, v1.w};
            bf16x8 hi, lo;
#pragma unroll
            for (int j = 0; j < 8; ++j) {
                __bf16 hh = (__bf16)f[j];
                hi[j] = hh;
                lo[j] = (__bf16)(f[j] - (float)hh);
            }
            bx[tg][h]     = hi;
            bx[tg][2 + h] = lo;
        }
    }

    float b1[4], b2[4]; int i1[4];
#pragma unroll
    for (int tg = 0; tg < 4; ++tg) { b1[tg] = -3e38f; b2[tg] = -3e38f; i1[tg] = 0; }

    // per-lane fragment base pointers (advance by cb*2048 elems)
    const __bf16* wp = wpk + (size_t)lane * 8;
    const float*  ep = e2n_g + q * 4;

    // r9-verified per-tg numerics: 6-deep chain; 4 independent chains
    // interleaved by depth -> 4-way MFMA ILP, no cross-chain adds.
    auto compute = [&](const bf16x8& A0, const bf16x8& A1, const bf16x8& A2,
                       const bf16x8& A3, const f32x4& EE, int cbase) {
        __builtin_amdgcn_s_setprio(1);
        f32x4 t0 = mfma16(A0, bx[0][0], EE);   // w_hi*x_hi d0-31
        f32x4 t1 = mfma16(A0, bx[1][0], EE);
        f32x4 t2 = mfma16(A0, bx[2][0], EE);
        f32x4 t3 = mfma16(A0, bx[3][0], EE);
        t0 = mfma16(A1, bx[0][1], t0);         // w_hi*x_hi d32-63
        t1 = mfma16(A1, bx[1][1], t1);
        t2 = mfma16(A1, bx[2][1], t2);
        t3 = mfma16(A1, bx[3][1], t3);
        t0 = mfma16(A0, bx[0][2], t0);         // w_hi*x_lo d0-31
        t1 = mfma16(A0, bx[1][2], t1);
        t2 = mfma16(A0, bx[2][2], t2);
        t3 = mfma16(A0, bx[3][2], t3);
        t0 = mfma16(A1, bx[0][3], t0);         // w_hi*x_lo d32-63
        t1 = mfma16(A1, bx[1][3], t1);
        t2 = mfma16(A1, bx[2][3], t2);
        t3 = mfma16(A1, bx[3][3], t3);
        t0 = mfma16(A2, bx[0][0], t0);         // w_lo*x_hi d0-31
        t1 = mfma16(A2, bx[1][0], t1);
        t2 = mfma16(A2, bx[2][0], t2);
        t3 = mfma16(A2, bx[3][0], t3);
        t0 = mfma16(A3, bx[0][1], t0);         // w_lo*x_hi d32-63
        t1 = mfma16(A3, bx[1][1], t1);
        t2 = mfma16(A3, bx[2][1], t2);
        t3 = mfma16(A3, bx[3][1], t3);
        __builtin_amdgcn_s_setprio(0);
        f32x4 tt[4] = {t0, t1, t2, t3};
        // Tracker: top-1 (value+idx, strict > => ties keep lower code)
        // + top-2 value (med3). Same op order as verified r5 numerics.
#pragma unroll
        for (int tg = 0; tg < 4; ++tg) {
#pragma unroll
            for (int r = 0; r < 4; ++r) {
                float a  = tt[tg][r];
                int iv   = cbase + q * 4 + r;
                bool gt  = a > b1[tg];
                i1[tg] = gt ? iv : i1[tg];
                b2[tg] = __builtin_amdgcn_fmed3f(a, b1[tg], b2[tg]);
                b1[tg] = fmaxf(a, b1[tg]);
            }
        }
    };

    // ---- main loop: 64 code blocks of 16; named-set ping-pong prefetch ----
    bf16x8 Pa0, Pa1, Pa2, Pa3, Pb0, Pb1, Pb2, Pb3;
    f32x4  Ea, Eb;

    {   // preload cb=0 -> set A
        const __bf16* wc = wp;
        Pa0 = *(const bf16x8*)(wc + 0);
        Pa1 = *(const bf16x8*)(wc + 512);
        Pa2 = *(const bf16x8*)(wc + 1024);
        Pa3 = *(const bf16x8*)(wc + 1536);
        Ea  = *(const f32x4*)(ep);
    }

    for (int cb = 0; cb < 64; cb += 2) {
        {   // prefetch cb+1 -> set B (issues before set-A compute waits)
            const __bf16* wc = wp + (size_t)(cb + 1) * 2048;
            Pb0 = *(const bf16x8*)(wc + 0);
            Pb1 = *(const bf16x8*)(wc + 512);
            Pb2 = *(const bf16x8*)(wc + 1024);
            Pb3 = *(const bf16x8*)(wc + 1536);
            Eb  = *(const f32x4*)(ep + (cb + 1) * 16);
        }
        compute(Pa0, Pa1, Pa2, Pa3, Ea, cb * 16);
        if (cb + 2 < 64) {   // prefetch cb+2 -> set A
            const __bf16* wc = wp + (size_t)(cb + 2) * 2048;
            Pa0 = *(const bf16x8*)(wc + 0);
            Pa1 = *(const bf16x8*)(wc + 512);
            Pa2 = *(const bf16x8*)(wc + 1024);
            Pa3 = *(const bf16x8*)(wc + 1536);
            Ea  = *(const f32x4*)(ep + (cb + 2) * 16);
        }
        compute(Pb0, Pb1, Pb2, Pb3, Eb, (cb + 1) * 16);
    }

    // ---- cross-quad merge: lanes m,m+16,m+32,m+48 hold disjoint code sets ----
    float B1f[4], B2f[4]; int I1f[4];
#pragma unroll
    for (int tg = 0; tg < 4; ++tg) {
        float B1 = b1[tg], B2 = b2[tg]; int I1 = i1[tg];
#pragma unroll
        for (int mask = 16; mask <= 32; mask <<= 1) {
            float ob1 = __shfl_xor(B1, mask);
            float ob2 = __shfl_xor(B2, mask);
            int   oi  = __shfl_xor(I1, mask);
            bool take = (ob1 > B1) || (ob1 == B1 && oi < I1);
            B2 = fmaxf(fminf(ob1, B1), fmaxf(ob2, B2));
            I1 = take ? oi : I1;
            B1 = fmaxf(ob1, B1);
        }
        B1f[tg] = B1; B2f[tg] = B2; I1f[tg] = I1;   // replicated across quads
    }

    // token t (0..63) of this wave -> its index; lane owns token `lane`
    int myidx;
    {
        int src = lane & 15;
        int v0 = __shfl(I1f[0], src);
        int v1 = __shfl(I1f[1], src);
        int v2 = __shfl(I1f[2], src);
        int v3 = __shfl(I1f[3], src);
        int hi2 = lane >> 4;            // which token group
        int va = (hi2 & 1) ? v1 : v0;
        int vb = (hi2 & 1) ? v3 : v2;
        myidx = (hi2 & 2) ? vb : va;
    }

    // ---- ballot-driven exact fp32 rescan of near-ties (round-1 numerics) ----
#pragma unroll
    for (int tg = 0; tg < 4; ++tg) {
        unsigned long long msk =
            __ballot((lane < 16) && (B1f[tg] - B2f[tg] < 2e-3f));
        while (msk) {
            int mm = __ffsll((unsigned long long)msk) - 1;
            msk &= msk - 1;
            int tloc = tg * 16 + mm;              // token within this wave (0..63)
            const float4* xr = (const float4*)(x + (tok0 + tloc) * DIMD);
            float bv = 3e38f; int bi = 0;
            for (int j = 0; j < 16; ++j) {
                int k = lane * 16 + j;
                const float4* wr = (const float4*)(wfull + (size_t)k * DIMD);
                float s = 0.f;
#pragma unroll
                for (int i = 0; i < 16; ++i) {
                    float4 xv = xr[i], wv4 = wr[i];
                    s = fmaf(xv.x, wv4.x, s); s = fmaf(xv.y, wv4.y, s);
                    s = fmaf(xv.z, wv4.z, s); s = fmaf(xv.w, wv4.w, s);
                }
                float dv = fmaf(-2.f, s, e2_g[k]);
                if (dv < bv) { bv = dv; bi = k; }  // ties -> lower k
            }
#pragma unroll
            for (int mask2 = 1; mask2 <= 32; mask2 <<= 1) {
                float ov = __shfl_xor(bv, mask2);
                int   oi = __shfl_xor(bi, mask2);
                bool take = (ov < bv) || (ov == bv && oi < bi);
                bv = take ? ov : bv;
                bi = take ? oi : bi;
            }
            myidx = (lane == tloc) ? bi : myidx;
        }
    }

    // ---- outputs (nontemporal: pure streaming, keep L2 for wpk/e2n) ----
    __builtin_nontemporal_store((float)myidx,
                                out + (size_t)MTOK * DIMD + tok0 + lane);

    // coalesced gather: per j, wave writes one contiguous 1KB segment;
    // codebook row read cooperatively (16 lanes per row, contiguous 256B)
    {
        float* obase = out + tok0 * DIMD;
#pragma unroll
        for (int j = 0; j < 16; ++j) {
            int srcl = j * 4 + (lane >> 4);        // token 0..63
            int gi   = __shfl(myidx, srcl);
            f32x4 v = *(const f32x4*)(wfull + (size_t)gi * DIMD + (lane & 15) * 4);
            __builtin_nontemporal_store(v, (f32x4*)(obase + j * 256 + lane * 4));
        }
    }
}

extern "C" void kernel_launch(void* const* d_in, const int* in_sizes, int n_in,
                              void* d_out, int out_size, void* d_ws, size_t ws_size,
                              hipStream_t stream) {
    const float* x = (const float*)d_in[0];
    const float* w = (const float*)d_in[1];
    float* out = (float*)d_out;

    // ws: [wpk 256K][e2n 4K][e2 4K]
    __bf16* wpk = (__bf16*)d_ws;
    float*  e2n = (float*)((char*)d_ws + 262144);
    float*  e2  = (float*)((char*)d_ws + 266240);

    prep_kernel<<<68, 256, 0, stream>>>(w, wpk, e2n, e2);
    vq_main<<<MTOK / TPB, 256, 0, stream>>>(x, w, wpk, e2n, e2, out);
}